// Round 8
// baseline (2219.178 us; speedup 1.0000x reference)
//
#include <hip/hip_runtime.h>

typedef float f32x4 __attribute__((ext_vector_type(4)));
typedef short bf16x8 __attribute__((ext_vector_type(8)));

#define SLEN 128
#define TLEN 127
#define VOC 36
#define NPROBS (4096*127*36)
#define MLOSS_OFF NPROBS
#define LOSS_OFF (NPROBS + 4096)

// packed weights (shorts): W0p[q16][G4][kt12][512], W1p[q16][G4][kt16][512], FCp[n3][kt8][512]
#define WS_W0 0
#define WS_W1 786432
#define WS_FC 1835008
#define WS_B0 1859584
#define WS_B1 1863680
#define NW0 393216
#define NW1 524288
#define NFC 12288

// pipeline buffers
#define WS_H0  2097152              // short[16 grp][2 slot][8 ktile][256 row][32 ch] = 4 MB
#define WS_H1  6291456              // same
#define WS_CTR 10485760             // flags: 16 grp x 16 blk x 128B line = 32 KB
#define WS_NEEDED 10518528

#define GRP 131072                  // shorts per group (2 slots)
#define SLOT 65536                  // shorts per slot

__device__ __forceinline__ short f2bf(float f){
  unsigned u = __float_as_uint(f);
  u += 0x7fffu + ((u >> 16) & 1u);
  return (short)(u >> 16);
}
__device__ __forceinline__ float fsig(float x){ return 1.0f/(1.0f + __expf(-x)); }
__device__ __forceinline__ float ftanh(float x){ return 1.0f - 2.0f/(1.0f + __expf(2.0f*x)); }

// ---- fine-grained coherent (MALL) accessors ----
__device__ __forceinline__ void ld16_sc(bf16x8* d, const short* p){
  asm volatile("global_load_dwordx4 %0, %1, off sc0 sc1" : "=&v"(*d) : "v"(p));
}
__device__ __forceinline__ void st2_sc(short* p, short v){
  asm volatile("global_store_short %0, %1, off sc0 sc1" :: "v"(p), "v"(v));
}
__device__ __forceinline__ unsigned ldflag_sc(const unsigned* p){
  unsigned r;
  asm volatile("global_load_dword %0, %1, off sc0 sc1\n\ts_waitcnt vmcnt(0)"
               : "=&v"(r) : "v"(p) : "memory");
  return r;
}
__device__ __forceinline__ void stflag_sc(unsigned* p, unsigned v){
  asm volatile("global_store_dword %0, %1, off sc0 sc1" :: "v"(p), "v"(v) : "memory");
}

__global__ void prep_kernel(const float* __restrict__ Wih0, const float* __restrict__ Whh0,
                            const float* __restrict__ bih0, const float* __restrict__ bhh0,
                            const float* __restrict__ Wih1, const float* __restrict__ Whh1,
                            const float* __restrict__ bih1, const float* __restrict__ bhh1,
                            const float* __restrict__ fcW,
                            short* __restrict__ w0, short* __restrict__ w1, short* __restrict__ fcw,
                            float* __restrict__ b0, float* __restrict__ b1,
                            float* __restrict__ out)
{
  int idx = blockIdx.x*256 + threadIdx.x;
  if (idx == 0) out[LOSS_OFF] = 0.0f;
  if (idx < NW0) {
    int wv = idx / 24576;
    int r1 = idx - wv*24576;
    int G  = r1 / 6144;
    int r2 = r1 - G*6144;
    int kt = r2 / 512;
    int r3 = r2 - kt*512;
    int ln = r3 >> 3, e = r3 & 7;
    int row = G*256 + wv*16 + (ln & 15);
    int col = kt*32 + (ln>>4)*8 + e;
    float v = (col < 128) ? Wih0[row*128 + col] : Whh0[row*256 + (col-128)];
    w0[idx] = f2bf(v);
  } else if (idx < NW0 + NW1) {
    int i2 = idx - NW0;
    int wv = i2 / 32768;
    int r1 = i2 - wv*32768;
    int G  = r1 / 8192;
    int r2 = r1 - G*8192;
    int kt = r2 / 512;
    int r3 = r2 - kt*512;
    int ln = r3 >> 3, e = r3 & 7;
    int row = G*256 + wv*16 + (ln & 15);
    int col = kt*32 + (ln>>4)*8 + e;
    float v = (col < 256) ? Wih1[row*256 + col] : Whh1[row*256 + (col-256)];
    w1[i2] = f2bf(v);
  } else if (idx < NW0 + NW1 + NFC) {
    int i2 = idx - (NW0 + NW1);
    int n  = i2 / 4096;
    int r1 = i2 - n*4096;
    int kt = r1 / 512;
    int r3 = r1 - kt*512;
    int ln = r3 >> 3, e = r3 & 7;
    int row = n*16 + (ln & 15);
    int col = kt*32 + (ln>>4)*8 + e;
    fcw[i2] = (row < VOC) ? f2bf(fcW[row*256 + col]) : (short)0;
  } else if (idx < NW0 + NW1 + NFC + 1024) {
    int i2 = idx - (NW0 + NW1 + NFC);
    b0[i2] = bih0[i2] + bhh0[i2];
  } else if (idx < NW0 + NW1 + NFC + 2048) {
    int i2 = idx - (NW0 + NW1 + NFC + 1024);
    b1[i2] = bih1[i2] + bhh1[i2];
  }
}

// ============ merged-per-wave persistent kernel ============
// 256 blocks, 1/CU. g = (b&7)+8*(b>>7), q = (b>>3)&15.
// Block q holds channels [16q,16q+16) of BOTH layers.
// Wave w owns rows 16w..16w+16 of the group for L0(t) AND L1(t-1);
// wave w==q additionally does FC/softmax for step t-2 (its rows == block's output rows).
__global__ __launch_bounds__(1024, 4)
void lstm_fuse(const int* __restrict__ x, const float* __restrict__ emb,
               const float* __restrict__ fcb,
               const short* __restrict__ W0, const short* __restrict__ W1,
               const short* __restrict__ FCW,
               const float* __restrict__ b0, const float* __restrict__ b1,
               short* __restrict__ h0b, short* __restrict__ h1b,
               unsigned* __restrict__ flags,
               float* __restrict__ out)
{
  extern __shared__ short lds[];
  short* Wl0  = lds;            // 24576 shorts (48 KB)
  short* Wl1  = lds + 24576;    // 32768 shorts (64 KB)
  short* fcs  = lds + 57344;    // 12288 shorts (24 KB)
  short* embs = lds + 69632;    // 36*136 = 4896 shorts
  float* invlen_l = (float*)(lds + 74528); // 16 floats

  const int tid  = threadIdx.x;
  const int lane = tid & 63;
  const int w    = tid >> 6;      // 0..15
  const int l15  = lane & 15;
  const int l4   = lane >> 4;

  const int b = blockIdx.x;
  const int g = (b & 7) + 8*(b >> 7);
  const int q = (b >> 3) & 15;

  unsigned* grp_flags = flags + g*512;          // 16 lines x 32 uints
  unsigned* my_flag   = grp_flags + q*32;
  short* gh0 = h0b + g*GRP;
  short* gh1 = h1b + g*GRP;

  // ---- prologue: stage LDS (panels pre-zeroed by memsetAsync) ----
  for (int i = tid; i < 24576; i += 1024) Wl0[i] = W0[q*24576 + i];
  for (int i = tid; i < 32768; i += 1024) Wl1[i] = W1[q*32768 + i];
  for (int i = tid; i < 12288; i += 1024) fcs[i] = FCW[i];
  for (int i = tid; i < 36*128; i += 1024) {
    int r = i >> 7, c = i & 127;
    embs[r*136 + c] = f2bf(emb[i]);
  }
  if (tid < 16) {
    int row = g*256 + q*16 + tid;
    int cnt = 0;
    for (int s = 0; s < SLEN; s++) cnt += (x[(size_t)row*SLEN + s] != 0) ? 1 : 0;
    invlen_l[tid] = 1.0f / (float)cnt;
  }
  __syncthreads();
  if (tid == 0) stflag_sc(my_flag, 1u);

  // hoisted invariants
  const int ch = 16*q + l15;
  const float bi0 = b0[ch], bf0 = b0[256+ch], bg0 = b0[512+ch], bo0 = b0[768+ch];
  const float bi1 = b1[ch], bf1 = b1[256+ch], bg1 = b1[512+ch], bo1 = b1[768+ch];
  const bool  v2  = (l15 < 4);
  const float lb0 = fcb[l15], lb1 = fcb[16 + l15];
  const float lb2 = v2 ? fcb[32 + l15] : 0.f;

  const int myrow = g*256 + 16*w + l15;          // A-operand row this lane feeds
  const int abase = (16*w + l15)*32 + l4*8;      // per-lane panel load offset (+ kt*8192)
  const int sbase = (q>>1)*8192 + (q&1)*16 + l15;// per-lane panel store offset (+ row*32)

  float c0s[4] = {}, c1s[4] = {};
  float mloss[4] = {0.f,0.f,0.f,0.f};

  for (int t = 0; t <= 128; t++) {
    const bool doL0 = (t <= 126);
    const bool doL1 = (t >= 1 && t <= 127);
    const bool doFC = (w == q) && (t >= 2);

    // ---- x loads pinned BEFORE the rendezvous (keep-alive materialization) ----
    int tok = 0;
    if (doL0) tok = x[(size_t)myrow*SLEN + t];
    int embb = tok*136 + l4*8;
    asm volatile("" : "+v"(embb));
    int tg4[4] = {0,0,0,0};
    if (doFC) {
      #pragma unroll
      for (int j = 0; j < 4; j++) {
        tg4[j] = x[(size_t)(g*256 + 16*q + 4*l4 + j)*SLEN + (t-1)];
        asm volatile("" : "+v"(tg4[j]));
      }
    }

    // ---- flag rendezvous: lane i polls sibling i's line ----
    if (tid < 16) {
      const unsigned* fp = grp_flags + tid*32;
      while (ldflag_sc(fp) < (unsigned)(t+1))
        __builtin_amdgcn_s_sleep(1);
    }
    __syncthreads();

    // ---- issue ALL panel loads up-front (SA: h0(t-1), SB: h1(t-2)) ----
    const short* h0src = gh0 + ((t^1)&1)*SLOT + abase;
    const short* h1src = gh1 + (t&1)*SLOT     + abase;
    bf16x8 SA[8], SB[8];
    #pragma unroll
    for (int i = 0; i < 8; i++) ld16_sc(&SA[i], h0src + i*8192);
    #pragma unroll
    for (int i = 0; i < 8; i++) ld16_sc(&SB[i], h1src + i*8192);

    f32x4 acc0[4] = {}, acc1[4] = {};

    // L0 emb part (LDS) — covers load latency
    if (doL0) {
      #pragma unroll
      for (int kt = 0; kt < 4; kt++) {
        bf16x8 A = *(const bf16x8*)(embs + embb + kt*32);
        #pragma unroll
        for (int G = 0; G < 4; G++) {
          bf16x8 Bf = *(const bf16x8*)(Wl0 + (G*12 + kt)*512 + lane*8);
          acc0[G] = __builtin_amdgcn_mfma_f32_16x16x32_bf16(A, Bf, acc0[G], 0, 0, 0);
        }
      }
    }

    asm volatile("s_waitcnt vmcnt(8)" ::: "memory");   // SA (oldest 8) complete
    __builtin_amdgcn_sched_barrier(0);

    if (doL0) {
      #pragma unroll
      for (int i = 0; i < 8; i++) {
        #pragma unroll
        for (int G = 0; G < 4; G++) {
          bf16x8 Bf = *(const bf16x8*)(Wl0 + (G*12 + 4 + i)*512 + lane*8);
          acc0[G] = __builtin_amdgcn_mfma_f32_16x16x32_bf16(SA[i], Bf, acc0[G], 0, 0, 0);
        }
      }
    }
    if (doL1) {
      #pragma unroll
      for (int i = 0; i < 8; i++) {
        #pragma unroll
        for (int G = 0; G < 4; G++) {
          bf16x8 Bf = *(const bf16x8*)(Wl1 + (G*16 + i)*512 + lane*8);
          acc1[G] = __builtin_amdgcn_mfma_f32_16x16x32_bf16(SA[i], Bf, acc1[G], 0, 0, 0);
        }
      }
    }

    asm volatile("s_waitcnt vmcnt(0)" ::: "memory");   // SB complete
    __builtin_amdgcn_sched_barrier(0);

    if (doL1) {
      #pragma unroll
      for (int i = 0; i < 8; i++) {
        #pragma unroll
        for (int G = 0; G < 4; G++) {
          bf16x8 Bf = *(const bf16x8*)(Wl1 + (G*16 + 8 + i)*512 + lane*8);
          acc1[G] = __builtin_amdgcn_mfma_f32_16x16x32_bf16(SB[i], Bf, acc1[G], 0, 0, 0);
        }
      }
    }

    // gates + panel stores
    if (doL0) {
      short* hdst = gh0 + (t&1)*SLOT + sbase;
      #pragma unroll
      for (int j = 0; j < 4; j++) {
        float iv = fsig (acc0[0][j] + bi0);
        float fv = fsig (acc0[1][j] + bf0);
        float gv = ftanh(acc0[2][j] + bg0);
        float ov = fsig (acc0[3][j] + bo0);
        float c  = fv * c0s[j] + iv * gv;
        c0s[j] = c;
        st2_sc(hdst + (16*w + 4*l4 + j)*32, f2bf(ov * ftanh(c)));
      }
    }
    if (doL1) {
      short* hdst = gh1 + ((t^1)&1)*SLOT + sbase;
      #pragma unroll
      for (int j = 0; j < 4; j++) {
        float iv = fsig (acc1[0][j] + bi1);
        float fv = fsig (acc1[1][j] + bf1);
        float gv = ftanh(acc1[2][j] + bg1);
        float ov = fsig (acc1[3][j] + bo1);
        float c  = fv * c1s[j] + iv * gv;
        c1s[j] = c;
        st2_sc(hdst + (16*w + 4*l4 + j)*32, f2bf(ov * ftanh(c)));
      }
    }

    // FC + softmax + loss for step t-2 (wave q; A-operand = SB, already in regs)
    if (doFC) {
      f32x4 a3[3] = {};
      #pragma unroll
      for (int i = 0; i < 8; i++) {
        #pragma unroll
        for (int n = 0; n < 3; n++) {
          bf16x8 Bf = *(const bf16x8*)(fcs + (n*8 + i)*512 + lane*8);
          a3[n] = __builtin_amdgcn_mfma_f32_16x16x32_bf16(SB[i], Bf, a3[n], 0, 0, 0);
        }
      }
      #pragma unroll
      for (int j = 0; j < 4; j++) {
        float g0 = fmaxf(a3[0][j] + lb0, 0.f);
        float g1 = fmaxf(a3[1][j] + lb1, 0.f);
        float g2 = v2 ? fmaxf(a3[2][j] + lb2, 0.f) : -INFINITY;
        float mx = fmaxf(fmaxf(g0, g1), g2);
        #pragma unroll
        for (int k = 1; k < 16; k <<= 1) mx = fmaxf(mx, __shfl_xor(mx, k, 64));
        float e0 = __expf(g0 - mx), e1 = __expf(g1 - mx);
        float e2 = v2 ? __expf(g2 - mx) : 0.f;
        float sm = e0 + e1 + e2;
        #pragma unroll
        for (int k = 1; k < 16; k <<= 1) sm += __shfl_xor(sm, k, 64);
        float inv = 1.0f / sm;
        int grow = g*256 + 16*q + 4*l4 + j;
        float* po = out + ((size_t)grow*TLEN + (t-2))*VOC;
        __builtin_nontemporal_store(e0 * inv, po + l15);
        __builtin_nontemporal_store(e1 * inv, po + 16 + l15);
        if (v2) __builtin_nontemporal_store(e2 * inv, po + 32 + l15);
        int tg = tg4[j];
        float sel = (tg < 16) ? g0 : ((tg < 32) ? g1 : g2);
        float ltg = __shfl(sel, (lane & 48) | (tg & 15), 64);
        float nll = mx + __logf(sm) - ltg;
        mloss[j] += (tg != 0) ? nll * invlen_l[4*l4 + j] : 0.f;
      }
    }

    // drain own panel stores, then rendezvous-post
    asm volatile("s_waitcnt vmcnt(0)" ::: "memory");
    __syncthreads();
    if (tid == 0 && t < 128)
      stflag_sc(my_flag, (unsigned)(t+2));
  } // tick loop

  if (w == q && l15 == 0) {
    float tot = 0.f;
    #pragma unroll
    for (int j = 0; j < 4; j++) {
      int grow = g*256 + 16*q + 4*l4 + j;
      __builtin_nontemporal_store(mloss[j], out + (size_t)MLOSS_OFF + grow);
      tot += mloss[j];
    }
    atomicAdd(out + LOSS_OFF, tot * (1.0f/4096.0f));
  }
}

// ===================== fallback (R2-style, ~9.6 ms) =====================
__global__ __launch_bounds__(1024, 4)
void lstm_small(const int* __restrict__ x, const float* __restrict__ emb,
                const float* __restrict__ fcb,
                const short* __restrict__ W0, const short* __restrict__ W1,
                const short* __restrict__ FCW,
                const float* __restrict__ b0, const float* __restrict__ b1,
                float* __restrict__ out)
{
  __shared__ __align__(16) short emb_s[36*136];
  __shared__ __align__(16) short h0_s[32*264];
  __shared__ __align__(16) short h1_s[32*264];
  __shared__ int   tok_s[32];
  __shared__ float invlen_s[32];

  const int tid  = threadIdx.x;
  const int lane = tid & 63;
  const int wv   = tid >> 6;
  const int l15  = lane & 15;
  const int l4   = lane >> 4;
  const int r0   = blockIdx.x * 32;

  for (int i = tid; i < 36*128; i += 1024) {
    int r = i >> 7, c = i & 127;
    emb_s[r*136 + c] = f2bf(emb[i]);
  }
  for (int i = tid; i < 32*264; i += 1024) { h0_s[i] = 0; h1_s[i] = 0; }
  if (tid < 32) {
    int cnt = 0;
    for (int s = 0; s < SLEN; s++) cnt += (x[(r0+tid)*SLEN + s] != 0) ? 1 : 0;
    invlen_s[tid] = 1.0f / (float)cnt;
    tok_s[tid] = x[(r0+tid)*SLEN + 0];
  }
  __syncthreads();

  const int ch = wv*16 + l15;
  const short* w0base = W0 + wv*24576 + lane*8;
  const short* w1base = W1 + wv*32768 + lane*8;
  const short* fcbase = FCW + lane*8;
  const float bi0 = b0[ch], bf0 = b0[256+ch], bg0 = b0[512+ch], bo0 = b0[768+ch];
  const float bi1 = b1[ch], bf1 = b1[256+ch], bg1 = b1[512+ch], bo1 = b1[768+ch];
  const bool  v2  = (l15 < 4);
  const float lb0 = fcb[l15], lb1 = fcb[16 + l15];
  const float lb2 = v2 ? fcb[32 + l15] : 0.f;

  float c0s[2][4] = {};
  float c1s[2][4] = {};
  float mloss[4] = {0.f,0.f,0.f,0.f};

  for (int t = 0; t < TLEN; t++) {
    int tokv[2];
    #pragma unroll
    for (int m = 0; m < 2; m++) tokv[m] = tok_s[m*16 + l15];
    float hn0[2][4];
    {
      f32x4 acc[2][4] = {};
      #pragma unroll
      for (int kt = 0; kt < 12; kt++) {
        bf16x8 Bf[4];
        #pragma unroll
        for (int G = 0; G < 4; G++) Bf[G] = *(const bf16x8*)(w0base + (G*12 + kt)*512);
        bf16x8 Af[2];
        #pragma unroll
        for (int m = 0; m < 2; m++) {
          if (kt < 4) Af[m] = *(const bf16x8*)(emb_s + tokv[m]*136 + kt*32 + l4*8);
          else        Af[m] = *(const bf16x8*)(h0_s + (m*16 + l15)*264 + (kt-4)*32 + l4*8);
        }
        #pragma unroll
        for (int m = 0; m < 2; m++)
          #pragma unroll
          for (int G = 0; G < 4; G++)
            acc[m][G] = __builtin_amdgcn_mfma_f32_16x16x32_bf16(Af[m], Bf[G], acc[m][G], 0, 0, 0);
      }
      #pragma unroll
      for (int m = 0; m < 2; m++)
        #pragma unroll
        for (int j = 0; j < 4; j++) {
          float iv = fsig (acc[m][0][j] + bi0);
          float fv = fsig (acc[m][1][j] + bf0);
          float gv = ftanh(acc[m][2][j] + bg0);
          float ov = fsig (acc[m][3][j] + bo0);
          float c  = fv * c0s[m][j] + iv * gv;
          c0s[m][j] = c;
          hn0[m][j] = ov * ftanh(c);
        }
    }
    __syncthreads();
    if (wv == 15 && lane < 32) tok_s[lane] = x[(r0+lane)*SLEN + t + 1];
    #pragma unroll
    for (int m = 0; m < 2; m++)
      #pragma unroll
      for (int j = 0; j < 4; j++)
        h0_s[(m*16 + l4*4 + j)*264 + ch] = f2bf(hn0[m][j]);
    __syncthreads();
    float hn1[2][4];
    {
      f32x4 acc[2][4] = {};
      #pragma unroll
      for (int kt = 0; kt < 16; kt++) {
        bf16x8 Bf[4];
        #pragma unroll
        for (int G = 0; G < 4; G++) Bf[G] = *(const bf16x8*)(w1base + (G*16 + kt)*512);
        bf16x8 Af[2];
        #pragma unroll
        for (int m = 0; m < 2; m++) {
          if (kt < 8) Af[m] = *(const bf16x8*)(h0_s + (m*16 + l15)*264 + kt*32 + l4*8);
          else        Af[m] = *(const bf16x8*)(h1_s + (m*16 + l15)*264 + (kt-8)*32 + l4*8);
        }
        #pragma unroll
        for (int m = 0; m < 2; m++)
          #pragma unroll
          for (int G = 0; G < 4; G++)
            acc[m][G] = __builtin_amdgcn_mfma_f32_16x16x32_bf16(Af[m], Bf[G], acc[m][G], 0, 0, 0);
      }
      #pragma unroll
      for (int m = 0; m < 2; m++)
        #pragma unroll
        for (int j = 0; j < 4; j++) {
          float iv = fsig (acc[m][0][j] + bi1);
          float fv = fsig (acc[m][1][j] + bf1);
          float gv = ftanh(acc[m][2][j] + bg1);
          float ov = fsig (acc[m][3][j] + bo1);
          float c  = fv * c1s[m][j] + iv * gv;
          c1s[m][j] = c;
          hn1[m][j] = ov * ftanh(c);
        }
    }
    __syncthreads();
    #pragma unroll
    for (int m = 0; m < 2; m++)
      #pragma unroll
      for (int j = 0; j < 4; j++)
        h1_s[(m*16 + l4*4 + j)*264 + ch] = f2bf(hn1[m][j]);
    __syncthreads();
    if (wv < 2) {
      const int wr = wv * 16;
      f32x4 a3[3] = {};
      #pragma unroll
      for (int kt = 0; kt < 8; kt++) {
        bf16x8 Ah = *(const bf16x8*)(h1_s + (wr + l15)*264 + kt*32 + l4*8);
        #pragma unroll
        for (int n = 0; n < 3; n++) {
          bf16x8 Bf = *(const bf16x8*)(fcbase + (n*8 + kt)*512);
          a3[n] = __builtin_amdgcn_mfma_f32_16x16x32_bf16(Ah, Bf, a3[n], 0, 0, 0);
        }
      }
      #pragma unroll
      for (int j = 0; j < 4; j++) {
        float g0 = fmaxf(a3[0][j] + lb0, 0.f);
        float g1 = fmaxf(a3[1][j] + lb1, 0.f);
        float g2 = v2 ? fmaxf(a3[2][j] + lb2, 0.f) : -INFINITY;
        float mx = fmaxf(fmaxf(g0, g1), g2);
        #pragma unroll
        for (int k = 1; k < 16; k <<= 1) mx = fmaxf(mx, __shfl_xor(mx, k, 64));
        float e0 = __expf(g0 - mx), e1 = __expf(g1 - mx);
        float e2 = v2 ? __expf(g2 - mx) : 0.f;
        float sm = e0 + e1 + e2;
        #pragma unroll
        for (int k = 1; k < 16; k <<= 1) sm += __shfl_xor(sm, k, 64);
        float inv = 1.0f / sm;
        int row = wr + l4*4 + j;
        float* po = out + ((size_t)(r0 + row)*TLEN + t)*VOC;
        __builtin_nontemporal_store(e0 * inv, po + l15);
        __builtin_nontemporal_store(e1 * inv, po + 16 + l15);
        if (v2) __builtin_nontemporal_store(e2 * inv, po + 32 + l15);
        int tg = tok_s[row];
        float sel = (tg < 16) ? g0 : ((tg < 32) ? g1 : g2);
        float ltg = __shfl(sel, (lane & 48) | (tg & 15), 64);
        float nll = mx + __logf(sm) - ltg;
        mloss[j] += (tg != 0) ? nll * invlen_s[row] : 0.f;
      }
    }
  }
  if (wv < 2 && l15 == 0) {
    float tot = 0.f;
    #pragma unroll
    for (int j = 0; j < 4; j++) {
      int row = wv*16 + l4*4 + j;
      __builtin_nontemporal_store(mloss[j], out + (size_t)MLOSS_OFF + r0 + row);
      tot += mloss[j];
    }
    atomicAdd(out + LOSS_OFF, tot * (1.0f/4096.0f));
  }
}

extern "C" void kernel_launch(void* const* d_in, const int* in_sizes, int n_in,
                              void* d_out, int out_size, void* d_ws, size_t ws_size,
                              hipStream_t stream) {
  const int*   x    = (const int*)  d_in[0];
  const float* emb  = (const float*)d_in[1];
  const float* Wih0 = (const float*)d_in[2];
  const float* Whh0 = (const float*)d_in[3];
  const float* bih0 = (const float*)d_in[4];
  const float* bhh0 = (const float*)d_in[5];
  const float* Wih1 = (const float*)d_in[6];
  const float* Whh1 = (const float*)d_in[7];
  const float* bih1 = (const float*)d_in[8];
  const float* bhh1 = (const float*)d_in[9];
  const float* fcW  = (const float*)d_in[10];
  const float* fcb  = (const float*)d_in[11];

  short* w0  = (short*)((char*)d_ws + WS_W0);
  short* w1  = (short*)((char*)d_ws + WS_W1);
  short* fcw = (short*)((char*)d_ws + WS_FC);
  float* b0  = (float*)((char*)d_ws + WS_B0);
  float* b1  = (float*)((char*)d_ws + WS_B1);
  float* out = (float*)d_out;

  bool big = (ws_size >= (size_t)WS_NEEDED);
  static int lds_ok = -1;
  if (big && lds_ok < 0) {
    hipError_t e = hipFuncSetAttribute((const void*)lstm_fuse,
                     hipFuncAttributeMaxDynamicSharedMemorySize, 149504);
    lds_ok = (e == hipSuccess) ? 1 : 0;
  }
  bool use_pipe = big && (lds_ok == 1);

  short*    h0bp = (short*)((char*)d_ws + WS_H0);
  short*    h1bp = (short*)((char*)d_ws + WS_H1);
  unsigned* ctr  = (unsigned*)((char*)d_ws + WS_CTR);

  prep_kernel<<<3640, 256, 0, stream>>>(Wih0, Whh0, bih0, bhh0, Wih1, Whh1,
                                        bih1, bhh1, fcW, w0, w1, fcw, b0, b1, out);
  if (use_pipe) {
    // zero panels + flags (kernel-boundary coherence; re-done every launch)
    hipMemsetAsync((char*)d_ws + WS_H0, 0, (size_t)(WS_NEEDED - WS_H0), stream);
    lstm_fuse<<<256, 1024, 149504, stream>>>(x, emb, fcb, w0, w1, fcw, b0, b1,
                                             h0bp, h1bp, ctr, out);
  } else {
    lstm_small<<<128, 1024, 0, stream>>>(x, emb, fcb, w0, w1, fcw, b0, b1, out);
  }
}